// Round 1
// baseline (521.307 us; speedup 1.0000x reference)
//
#include <hip/hip_runtime.h>
#include <cmath>

// Workspace layout (in floats):
//   fq_all : 0       .. 245760   (256 x (64+128+256+512))
//   r2_all : 245760  .. 253760   (4 x 2000)
//   lid    : 253760  .. 254784   (256 x 4, [b][layer])
//   G_all  : 262144  .. 2310144  (4 x 256 x 2000)   total ~9.3 MB
#define WS_FQ_OFF      0u
#define WS_R2_OFF      245760u
#define WS_LID_OFF     253760u
#define WS_G_OFF       262144u
#define G_LAYER_STRIDE 512000u
#define NREF           2000

// ---------------------------------------------------------------- pooling
// One wave (64 lanes) per (b,c) row; 4 waves per 256-thread block.
__global__ __launch_bounds__(256) void pool_kernel(const float* __restrict__ feat,
                                                   float* __restrict__ fq,
                                                   int HW, float invHW) {
    int w = threadIdx.x >> 6, lane = threadIdx.x & 63;
    size_t row = (size_t)blockIdx.x * 4 + w;
    const float* p = feat + row * (size_t)HW;
    float s = 0.f;
    if ((HW & 3) == 0) {
        const float4* p4 = (const float4*)p;   // row base 16B-aligned for HW%4==0 layers
        int n4 = HW >> 2;
        for (int i = lane; i < n4; i += 64) {
            float4 v = p4[i];
            s += (v.x + v.y) + (v.z + v.w);
        }
    } else {
        for (int i = lane; i < HW; i += 64) s += p[i];
    }
    #pragma unroll
    for (int off = 32; off; off >>= 1) s += __shfl_down(s, off, 64);
    if (lane == 0) fq[row] = s * invHW;
}

// ---------------------------------------------------------------- ref norms
__global__ __launch_bounds__(256) void r2_kernel(const float* __restrict__ ref0,
                                                 const float* __restrict__ ref1,
                                                 const float* __restrict__ ref2,
                                                 const float* __restrict__ ref3,
                                                 float* __restrict__ r2_all) {
    int layer = blockIdx.y;
    int w = threadIdx.x >> 6, lane = threadIdx.x & 63;
    int r = blockIdx.x * 4 + w;
    if (r >= NREF) return;
    const float* rp; int C;
    switch (layer) {
        case 0:  rp = ref0; C = 64;  break;
        case 1:  rp = ref1; C = 128; break;
        case 2:  rp = ref2; C = 256; break;
        default: rp = ref3; C = 512; break;
    }
    const float4* row = (const float4*)(rp + (size_t)r * C);
    int n4 = C >> 2;
    float s = 0.f;
    for (int i = lane; i < n4; i += 64) {
        float4 v = row[i];
        s += v.x*v.x + v.y*v.y + v.z*v.z + v.w*v.w;
    }
    #pragma unroll
    for (int off = 32; off; off >>= 1) s += __shfl_down(s, off, 64);
    if (lane == 0) r2_all[layer * NREF + r] = s;
}

// ---------------------------------------------------------------- G = fq @ ref^T
// fp32 (no fp32 MFMA on CDNA4). 64x64 output tile, BK=32, 256 threads, 4x4 acc.
#define BM 64
#define BN 64
#define BK 32
#define LDT 68   // padded LDS stride: 68*4B = 272B = 16*17 -> float4-aligned rows
__global__ __launch_bounds__(256) void gemm_qr(const float* __restrict__ A,   // [256][K]
                                               const float* __restrict__ B,   // [NREF][K]
                                               float* __restrict__ G,         // [256][NREF]
                                               int K, int N) {
    __shared__ __align__(16) float As[BK * LDT];
    __shared__ __align__(16) float Bs[BK * LDT];
    int t = threadIdx.x;
    int tq = t & 15, tr = t >> 4;           // 16x16 thread grid -> 4x4 outputs each
    int m0 = blockIdx.x * BM;
    int n0 = blockIdx.y * BN;
    int row0 = t >> 3;                       // 0..31
    int kc4  = t & 7;                        // which float4 along K
    float acc[4][4] = {};

    for (int k0 = 0; k0 < K; k0 += BK) {
        #pragma unroll
        for (int half = 0; half < 2; ++half) {
            int row = row0 + half * 32;
            float4 av = *(const float4*)(A + (size_t)(m0 + row) * K + k0 + kc4 * 4);
            int brow = n0 + row;
            float4 bv = make_float4(0.f, 0.f, 0.f, 0.f);
            if (brow < N) bv = *(const float4*)(B + (size_t)brow * K + k0 + kc4 * 4);
            As[(kc4*4 + 0) * LDT + row] = av.x;
            As[(kc4*4 + 1) * LDT + row] = av.y;
            As[(kc4*4 + 2) * LDT + row] = av.z;
            As[(kc4*4 + 3) * LDT + row] = av.w;
            Bs[(kc4*4 + 0) * LDT + row] = bv.x;
            Bs[(kc4*4 + 1) * LDT + row] = bv.y;
            Bs[(kc4*4 + 2) * LDT + row] = bv.z;
            Bs[(kc4*4 + 3) * LDT + row] = bv.w;
        }
        __syncthreads();
        #pragma unroll
        for (int kk = 0; kk < BK; ++kk) {
            float4 a = *(const float4*)&As[kk * LDT + tq * 4];
            float4 b = *(const float4*)&Bs[kk * LDT + tr * 4];
            acc[0][0] += a.x*b.x; acc[0][1] += a.x*b.y; acc[0][2] += a.x*b.z; acc[0][3] += a.x*b.w;
            acc[1][0] += a.y*b.x; acc[1][1] += a.y*b.y; acc[1][2] += a.y*b.z; acc[1][3] += a.y*b.w;
            acc[2][0] += a.z*b.x; acc[2][1] += a.z*b.y; acc[2][2] += a.z*b.z; acc[2][3] += a.z*b.w;
            acc[3][0] += a.w*b.x; acc[3][1] += a.w*b.y; acc[3][2] += a.w*b.z; acc[3][3] += a.w*b.w;
        }
        __syncthreads();
    }

    int rbase = n0 + tr * 4;
    if (rbase < N) {    // N%4==0 -> a float4 group is all-valid or all-invalid
        #pragma unroll
        for (int i = 0; i < 4; ++i) {
            float4 o = make_float4(acc[i][0], acc[i][1], acc[i][2], acc[i][3]);
            *(float4*)(G + (size_t)(m0 + tq*4 + i) * N + rbase) = o;
        }
    }
}

// ---------------------------------------------------------------- top-k + LID
// One block per (query b, layer). d2 assembled in LDS; k+1 iterative argmins.
__global__ __launch_bounds__(256) void topk_lid_kernel(const float* __restrict__ fq_all,
                                                       const float* __restrict__ G_all,
                                                       const float* __restrict__ r2_all,
                                                       float* __restrict__ lid,
                                                       const int* __restrict__ kptr) {
    __shared__ float d2s[NREF];
    __shared__ float wsum[4];
    __shared__ unsigned long long redmin[4];
    __shared__ float sel[64];

    const int Cs[4]  = {64, 128, 256, 512};
    const int fqo[4] = {0, 16384, 49152, 114688};

    int b = blockIdx.x, layer = blockIdx.y;
    int t = threadIdx.x;
    int k = kptr[0];
    if (k > 63) k = 63;
    int C = Cs[layer];
    const float* fq = fq_all + fqo[layer] + (size_t)b * C;
    const float* G  = G_all + (size_t)layer * G_LAYER_STRIDE + (size_t)b * NREF;
    const float* r2 = r2_all + layer * NREF;

    // ||q||^2
    float s = 0.f;
    for (int c = t; c < C; c += 256) { float v = fq[c]; s += v * v; }
    #pragma unroll
    for (int off = 32; off; off >>= 1) s += __shfl_down(s, off, 64);
    if ((t & 63) == 0) wsum[t >> 6] = s;
    __syncthreads();
    float q2 = wsum[0] + wsum[1] + wsum[2] + wsum[3];

    // d2 = max(q2 - 2 q.r + r2, 0)
    for (int r = t; r < NREF; r += 256) {
        float v = q2 - 2.f * G[r] + r2[r];
        d2s[r] = v > 0.f ? v : 0.f;
    }
    __syncthreads();

    // k+1 smallest, ascending; stable (lowest index wins ties) like lax.top_k
    int nsel = k + 1;
    for (int it = 0; it < nsel; ++it) {
        unsigned long long best = ~0ull;
        for (int r = t; r < NREF; r += 256) {
            unsigned long long key = ((unsigned long long)__float_as_uint(d2s[r]) << 32)
                                     | (unsigned)r;
            if (key < best) best = key;
        }
        #pragma unroll
        for (int off = 32; off; off >>= 1) {
            unsigned long long o = __shfl_down(best, off, 64);
            if (o < best) best = o;
        }
        if ((t & 63) == 0) redmin[t >> 6] = best;
        __syncthreads();
        if (t == 0) {
            unsigned long long m = redmin[0];
            #pragma unroll
            for (int w = 1; w < 4; ++w) if (redmin[w] < m) m = redmin[w];
            int idx = (int)(m & 0xffffffffu);
            sel[it] = __uint_as_float((unsigned)(m >> 32));
            d2s[idx] = __uint_as_float(0x7f800000u);   // +inf sentinel
        }
        __syncthreads();
    }

    if (t == 0) {
        // d_i = sqrt(sel[i]); LID = -k / sum_{i=1..k} log(d_i/d_k)
        //     = -k / (0.5 * (sum_{i=1..k} log sel[i] - k * log sel[k]))
        float lk = logf(sel[k]);
        float ssum = 0.f;
        for (int i = 1; i <= k; ++i) ssum += (logf(sel[i]) - lk);
        lid[b * 4 + layer] = -(float)k / (0.5f * ssum);
    }
}

// ---------------------------------------------------------------- head
__global__ __launch_bounds__(256) void head_kernel(const float* __restrict__ lid,
                                                   const float* __restrict__ w,
                                                   const float* __restrict__ bias,
                                                   float* __restrict__ out) {
    int b = threadIdx.x;
    float acc = bias[0];
    #pragma unroll
    for (int l = 0; l < 4; ++l) acc += lid[b * 4 + l] * w[l];
    out[b] = 1.f / (1.f + expf(-acc));
}

extern "C" void kernel_launch(void* const* d_in, const int* in_sizes, int n_in,
                              void* d_out, int out_size, void* d_ws, size_t ws_size,
                              hipStream_t stream) {
    // dict order: feat0, ref0, feat1, ref1, feat2, ref2, feat3, ref3, reg_w, reg_b, k
    const float* feat[4] = {(const float*)d_in[0], (const float*)d_in[2],
                            (const float*)d_in[4], (const float*)d_in[6]};
    const float* ref[4]  = {(const float*)d_in[1], (const float*)d_in[3],
                            (const float*)d_in[5], (const float*)d_in[7]};
    const float* reg_w = (const float*)d_in[8];
    const float* reg_b = (const float*)d_in[9];
    const int*   kptr  = (const int*)d_in[10];

    float* ws     = (float*)d_ws;
    float* fq_all = ws + WS_FQ_OFF;
    float* r2_all = ws + WS_R2_OFF;
    float* lid    = ws + WS_LID_OFF;
    float* G_all  = ws + WS_G_OFF;

    const int Cs[4]  = {64, 128, 256, 512};
    const int HWs[4] = {3136, 784, 196, 49};
    const int fqo[4] = {0, 16384, 49152, 114688};

    for (int l = 0; l < 4; ++l) {
        int rows = 256 * Cs[l];
        pool_kernel<<<rows / 4, 256, 0, stream>>>(feat[l], fq_all + fqo[l],
                                                  HWs[l], 1.0f / (float)HWs[l]);
    }
    r2_kernel<<<dim3(NREF / 4, 4), 256, 0, stream>>>(ref[0], ref[1], ref[2], ref[3], r2_all);
    for (int l = 0; l < 4; ++l) {
        gemm_qr<<<dim3(256 / BM, (NREF + BN - 1) / BN), 256, 0, stream>>>(
            fq_all + fqo[l], ref[l], G_all + (size_t)l * G_LAYER_STRIDE, Cs[l], NREF);
    }
    topk_lid_kernel<<<dim3(256, 4), 256, 0, stream>>>(fq_all, G_all, r2_all, lid, kptr);
    head_kernel<<<1, 256, 0, stream>>>(lid, reg_w, reg_b, (float*)d_out);
}

// Round 2
// 481.523 us; speedup vs baseline: 1.0826x; 1.0826x over previous
//
#include <hip/hip_runtime.h>
#include <cmath>

// Workspace layout (in floats):
//   fq_all : 0       .. 245760   (256 x (64+128+256+512))
//   r2_all : 245760  .. 253760   (4 x 2000)
//   lid    : 253760  .. 254784   (256 x 4, [b][layer])
//   G_part : 262144  ..          (15 chunks x 256 x 2000)  ~31 MB total
#define WS_FQ_OFF      0u
#define WS_R2_OFF      245760u
#define WS_LID_OFF     253760u
#define WS_G_OFF       262144u
#define G_CHUNK_STRIDE 512000u
#define NREF           2000
#define KC             64       // split-K chunk width

// ---------------------------------------------------------------- pooling
// One wave (64 lanes) per (b,c) row; 4 waves per 256-thread block.
__global__ __launch_bounds__(256) void pool_kernel(const float* __restrict__ feat,
                                                   float* __restrict__ fq,
                                                   int HW, float invHW) {
    int w = threadIdx.x >> 6, lane = threadIdx.x & 63;
    size_t row = (size_t)blockIdx.x * 4 + w;
    const float* p = feat + row * (size_t)HW;
    float s = 0.f;
    if ((HW & 3) == 0) {
        const float4* p4 = (const float4*)p;
        int n4 = HW >> 2;
        for (int i = lane; i < n4; i += 64) {
            float4 v = p4[i];
            s += (v.x + v.y) + (v.z + v.w);
        }
    } else {
        for (int i = lane; i < HW; i += 64) s += p[i];
    }
    #pragma unroll
    for (int off = 32; off; off >>= 1) s += __shfl_down(s, off, 64);
    if (lane == 0) fq[row] = s * invHW;
}

// ---------------------------------------------------------------- ref norms
__global__ __launch_bounds__(256) void r2_kernel(const float* __restrict__ ref0,
                                                 const float* __restrict__ ref1,
                                                 const float* __restrict__ ref2,
                                                 const float* __restrict__ ref3,
                                                 float* __restrict__ r2_all) {
    int layer = blockIdx.y;
    int w = threadIdx.x >> 6, lane = threadIdx.x & 63;
    int r = blockIdx.x * 4 + w;
    if (r >= NREF) return;
    const float* rp; int C;
    switch (layer) {
        case 0:  rp = ref0; C = 64;  break;
        case 1:  rp = ref1; C = 128; break;
        case 2:  rp = ref2; C = 256; break;
        default: rp = ref3; C = 512; break;
    }
    const float4* row = (const float4*)(rp + (size_t)r * C);
    int n4 = C >> 2;
    float s = 0.f;
    for (int i = lane; i < n4; i += 64) {
        float4 v = row[i];
        s += v.x*v.x + v.y*v.y + v.z*v.z + v.w*v.w;
    }
    #pragma unroll
    for (int off = 32; off; off >>= 1) s += __shfl_down(s, off, 64);
    if (lane == 0) r2_all[layer * NREF + r] = s;
}

// ---------------------------------------------------------------- G = fq @ ref^T  (split-K)
// fp32 (no fp32 MFMA on CDNA4). 64x64 output tile, BK=32, 256 threads, 4x4 acc.
// blockIdx.z = K-chunk; each chunk covers KC=64 of K and writes its own partial slice.
#define BM 64
#define BN 64
#define BK 32
#define LDT 68
__global__ __launch_bounds__(256) void gemm_qr(const float* __restrict__ A,   // [256][K]
                                               const float* __restrict__ B,   // [NREF][K]
                                               float* __restrict__ Gp,        // [chunks][256][NREF]
                                               int K, int N) {
    __shared__ __align__(16) float As[BK * LDT];
    __shared__ __align__(16) float Bs[BK * LDT];
    int t = threadIdx.x;
    int tq = t & 15, tr = t >> 4;
    int m0 = blockIdx.x * BM;
    int n0 = blockIdx.y * BN;
    int kb = blockIdx.z * KC;
    int row0 = t >> 3;
    int kc4  = t & 7;
    float acc[4][4] = {};

    for (int k0 = kb; k0 < kb + KC; k0 += BK) {
        #pragma unroll
        for (int half = 0; half < 2; ++half) {
            int row = row0 + half * 32;
            float4 av = *(const float4*)(A + (size_t)(m0 + row) * K + k0 + kc4 * 4);
            int brow = n0 + row;
            float4 bv = make_float4(0.f, 0.f, 0.f, 0.f);
            if (brow < N) bv = *(const float4*)(B + (size_t)brow * K + k0 + kc4 * 4);
            As[(kc4*4 + 0) * LDT + row] = av.x;
            As[(kc4*4 + 1) * LDT + row] = av.y;
            As[(kc4*4 + 2) * LDT + row] = av.z;
            As[(kc4*4 + 3) * LDT + row] = av.w;
            Bs[(kc4*4 + 0) * LDT + row] = bv.x;
            Bs[(kc4*4 + 1) * LDT + row] = bv.y;
            Bs[(kc4*4 + 2) * LDT + row] = bv.z;
            Bs[(kc4*4 + 3) * LDT + row] = bv.w;
        }
        __syncthreads();
        #pragma unroll
        for (int kk = 0; kk < BK; ++kk) {
            float4 a = *(const float4*)&As[kk * LDT + tq * 4];
            float4 b = *(const float4*)&Bs[kk * LDT + tr * 4];
            acc[0][0] += a.x*b.x; acc[0][1] += a.x*b.y; acc[0][2] += a.x*b.z; acc[0][3] += a.x*b.w;
            acc[1][0] += a.y*b.x; acc[1][1] += a.y*b.y; acc[1][2] += a.y*b.z; acc[1][3] += a.y*b.w;
            acc[2][0] += a.z*b.x; acc[2][1] += a.z*b.y; acc[2][2] += a.z*b.z; acc[2][3] += a.z*b.w;
            acc[3][0] += a.w*b.x; acc[3][1] += a.w*b.y; acc[3][2] += a.w*b.z; acc[3][3] += a.w*b.w;
        }
        __syncthreads();
    }

    float* Gout = Gp + (size_t)blockIdx.z * G_CHUNK_STRIDE;
    int rbase = n0 + tr * 4;
    if (rbase < N) {
        #pragma unroll
        for (int i = 0; i < 4; ++i) {
            float4 o = make_float4(acc[i][0], acc[i][1], acc[i][2], acc[i][3]);
            *(float4*)(Gout + (size_t)(m0 + tq*4 + i) * N + rbase) = o;
        }
    }
}

// ---------------------------------------------------------------- top-k + LID via radix histogram
// One block per (query b, layer). Positive-float bits order like uints, so
// bin = bits>>20 (11 bits, 2048 bins). LID needs only the MULTISET of the
// k+1 smallest d2: sum of logs, min (dropped NN), max (d_k) — tie-break free.
__global__ __launch_bounds__(256) void topk_lid_kernel(const float* __restrict__ fq_all,
                                                       const float* __restrict__ G_all,
                                                       const float* __restrict__ r2_all,
                                                       float* __restrict__ lid,
                                                       const int* __restrict__ kptr) {
    __shared__ __align__(16) float d2s[NREF];
    __shared__ unsigned hist[2048];          // reused as candidate buffer later
    __shared__ float redq[4], redm[4], redl[4];
    __shared__ unsigned long long red8[4];
    __shared__ int sh_B, sh_cbelow, sh_cnt;
    __shared__ float sh_dmin;

    const int Cs[4]   = {64, 128, 256, 512};
    const int fqo[4]  = {0, 16384, 49152, 114688};
    const int nchs[4] = {1, 2, 4, 8};
    const int coff[4] = {0, 1, 3, 7};

    int b = blockIdx.x, layer = blockIdx.y;
    int t = threadIdx.x;
    int lane = t & 63, w = t >> 6;
    int k = kptr[0];
    if (k + 1 > NREF) k = NREF - 1;
    unsigned K1 = (unsigned)(k + 1);
    int C = Cs[layer];
    int nch = nchs[layer];
    const float* fq = fq_all + fqo[layer] + (size_t)b * C;
    const float* Gb = G_all + (size_t)coff[layer] * G_CHUNK_STRIDE + (size_t)b * NREF;
    const float* r2 = r2_all + layer * NREF;
    const float INF = __uint_as_float(0x7f800000u);

    // init hist + ||q||^2 partials
    for (int i = t; i < 2048; i += 256) hist[i] = 0u;
    if (t == 0) sh_cnt = 0;
    float s = 0.f;
    for (int c = t; c < C; c += 256) { float v = fq[c]; s += v * v; }
    #pragma unroll
    for (int off = 32; off; off >>= 1) s += __shfl_down(s, off, 64);
    if (lane == 0) redq[w] = s;
    __syncthreads();                                   // B1
    float q2 = redq[0] + redq[1] + redq[2] + redq[3];

    // pass A: d2 = max(q2 - 2*sum_c G_c + r2, 0); histogram; global min
    float minv = INF;
    for (int i = t; i < NREF / 4; i += 256) {
        float4 g = make_float4(0.f, 0.f, 0.f, 0.f);
        for (int c = 0; c < nch; ++c) {
            float4 v = *(const float4*)(Gb + (size_t)c * G_CHUNK_STRIDE + i * 4);
            g.x += v.x; g.y += v.y; g.z += v.z; g.w += v.w;
        }
        float4 rr = *(const float4*)(r2 + i * 4);
        float d0 = q2 - 2.f * g.x + rr.x; d0 = d0 > 0.f ? d0 : 0.f;
        float d1 = q2 - 2.f * g.y + rr.y; d1 = d1 > 0.f ? d1 : 0.f;
        float d2_ = q2 - 2.f * g.z + rr.z; d2_ = d2_ > 0.f ? d2_ : 0.f;
        float d3 = q2 - 2.f * g.w + rr.w; d3 = d3 > 0.f ? d3 : 0.f;
        *(float4*)(d2s + i * 4) = make_float4(d0, d1, d2_, d3);
        atomicAdd(&hist[__float_as_uint(d0) >> 20], 1u);
        atomicAdd(&hist[__float_as_uint(d1) >> 20], 1u);
        atomicAdd(&hist[__float_as_uint(d2_) >> 20], 1u);
        atomicAdd(&hist[__float_as_uint(d3) >> 20], 1u);
        minv = fminf(minv, fminf(fminf(d0, d1), fminf(d2_, d3)));
    }
    #pragma unroll
    for (int off = 32; off; off >>= 1) minv = fminf(minv, __shfl_down(minv, off, 64));
    if (lane == 0) redm[w] = minv;
    __syncthreads();                                   // B2

    // wave0: scan 2048 bins (32/lane) to find bin B holding rank k+1
    if (t < 64) {
        unsigned p = 0;
        int base = t * 32;
        #pragma unroll 4
        for (int i = 0; i < 32; ++i) p += hist[base + i];
        unsigned cum = p;
        #pragma unroll
        for (int off = 1; off < 64; off <<= 1) {
            unsigned o = __shfl_up(cum, off, 64);
            if (t >= off) cum += o;
        }
        unsigned excl = cum - p;
        if (excl < K1 && K1 <= cum) {
            unsigned run = excl;
            int binB = base;
            for (int i = 0; i < 32; ++i) {
                unsigned c = hist[base + i];
                if (run + c >= K1) { binB = base + i; break; }
                run += c;
            }
            sh_B = binB;
            sh_cbelow = (int)run;
        }
        if (t == 0) sh_dmin = fminf(fminf(redm[0], redm[1]), fminf(redm[2], redm[3]));
    }
    __syncthreads();                                   // B3 (scan done; hist reusable)

    // pass B: sum logs of values strictly below bin B (< k of them); compact bin-B candidates
    int B = sh_B;
    float* cand = (float*)hist;
    float lsum = 0.f;
    for (int i = t; i < NREF; i += 256) {
        float v = d2s[i];
        int bin = (int)(__float_as_uint(v) >> 20);
        if (bin < B) {
            lsum += logf(v);
        } else if (bin == B) {
            int pos = atomicAdd(&sh_cnt, 1);
            cand[pos] = v;
        }
    }
    #pragma unroll
    for (int off = 32; off; off >>= 1) lsum += __shfl_down(lsum, off, 64);
    if (lane == 0) redl[w] = lsum;
    __syncthreads();                                   // B4

    int cnt = sh_cnt;
    int m = (int)K1 - sh_cbelow;                       // 1 <= m <= cnt
    if (cnt <= 64) {
        // selection entirely in wave0 registers — no barriers
        if (t < 64) {
            float mv = (t < cnt) ? cand[t] : INF;
            float csum = 0.f, dk = 0.f;
            for (int it = 0; it < m; ++it) {
                float x = mv;
                #pragma unroll
                for (int off = 32; off; off >>= 1) x = fminf(x, __shfl_xor(x, off, 64));
                csum += logf(x);
                dk = x;
                unsigned long long ball = __ballot(mv == x);
                int src = __ffsll(ball) - 1;
                if (t == src) mv = INF;
            }
            if (t == 0) {
                float lsum_tot = redl[0] + redl[1] + redl[2] + redl[3];
                float denom = 0.5f * (lsum_tot + csum - logf(sh_dmin) - (float)k * logf(dk));
                lid[b * 4 + layer] = -(float)k / denom;
            }
        }
    } else {
        // robust fallback: block-wide iterative argmin over candidates
        float csum = 0.f, dk = 0.f;
        for (int it = 0; it < m; ++it) {
            unsigned long long best = ~0ull;
            for (int i = t; i < cnt; i += 256) {
                unsigned long long key =
                    ((unsigned long long)__float_as_uint(cand[i]) << 32) | (unsigned)i;
                if (key < best) best = key;
            }
            #pragma unroll
            for (int off = 32; off; off >>= 1) {
                unsigned long long o = __shfl_down(best, off, 64);
                if (o < best) best = o;
            }
            if (lane == 0) red8[w] = best;
            __syncthreads();
            unsigned long long mm = red8[0];
            #pragma unroll
            for (int ww = 1; ww < 4; ++ww) if (red8[ww] < mm) mm = red8[ww];
            float v = __uint_as_float((unsigned)(mm >> 32));
            if (t == 0) {
                csum += logf(v);
                dk = v;
                cand[(int)(mm & 0xffffffffu)] = INF;
            }
            __syncthreads();
        }
        if (t == 0) {
            float lsum_tot = redl[0] + redl[1] + redl[2] + redl[3];
            float denom = 0.5f * (lsum_tot + csum - logf(sh_dmin) - (float)k * logf(dk));
            lid[b * 4 + layer] = -(float)k / denom;
        }
    }
}

// ---------------------------------------------------------------- head
__global__ __launch_bounds__(256) void head_kernel(const float* __restrict__ lid,
                                                   const float* __restrict__ w,
                                                   const float* __restrict__ bias,
                                                   float* __restrict__ out) {
    int b = threadIdx.x;
    float acc = bias[0];
    #pragma unroll
    for (int l = 0; l < 4; ++l) acc += lid[b * 4 + l] * w[l];
    out[b] = 1.f / (1.f + expf(-acc));
}

extern "C" void kernel_launch(void* const* d_in, const int* in_sizes, int n_in,
                              void* d_out, int out_size, void* d_ws, size_t ws_size,
                              hipStream_t stream) {
    // dict order: feat0, ref0, feat1, ref1, feat2, ref2, feat3, ref3, reg_w, reg_b, k
    const float* feat[4] = {(const float*)d_in[0], (const float*)d_in[2],
                            (const float*)d_in[4], (const float*)d_in[6]};
    const float* ref[4]  = {(const float*)d_in[1], (const float*)d_in[3],
                            (const float*)d_in[5], (const float*)d_in[7]};
    const float* reg_w = (const float*)d_in[8];
    const float* reg_b = (const float*)d_in[9];
    const int*   kptr  = (const int*)d_in[10];

    float* ws     = (float*)d_ws;
    float* fq_all = ws + WS_FQ_OFF;
    float* r2_all = ws + WS_R2_OFF;
    float* lid    = ws + WS_LID_OFF;
    float* G_part = ws + WS_G_OFF;

    const int Cs[4]   = {64, 128, 256, 512};
    const int HWs[4]  = {3136, 784, 196, 49};
    const int fqo[4]  = {0, 16384, 49152, 114688};
    const int coff[4] = {0, 1, 3, 7};

    for (int l = 0; l < 4; ++l) {
        int rows = 256 * Cs[l];
        pool_kernel<<<rows / 4, 256, 0, stream>>>(feat[l], fq_all + fqo[l],
                                                  HWs[l], 1.0f / (float)HWs[l]);
    }
    r2_kernel<<<dim3(NREF / 4, 4), 256, 0, stream>>>(ref[0], ref[1], ref[2], ref[3], r2_all);
    for (int l = 0; l < 4; ++l) {
        int chunks = Cs[l] / KC;   // {1,2,4,8}
        gemm_qr<<<dim3(256 / BM, (NREF + BN - 1) / BN, chunks), 256, 0, stream>>>(
            fq_all + fqo[l], ref[l], G_part + (size_t)coff[l] * G_CHUNK_STRIDE, Cs[l], NREF);
    }
    topk_lid_kernel<<<dim3(256, 4), 256, 0, stream>>>(fq_all, G_part, r2_all, lid, kptr);
    head_kernel<<<1, 256, 0, stream>>>(lid, reg_w, reg_b, (float*)d_out);
}